// Round 1
// baseline (305.502 us; speedup 1.0000x reference)
//
#include <hip/hip_runtime.h>
#include <math.h>

#define NUM_ENT 10000
#define NUM_REL 230
#define R2      (2*NUM_REL)   // 460
#define S_DIM   96
#define T_DIM   32
#define DIM     128
#define N_NBR   32768
#define Q_ENT   4096
#define E_EDGE  32768
#define B_TRI   1024
#define BN_EPS  1e-5f

// ---------------------------------------------------------------------------
// K1: per-neighbor feature + per-relation matvec z = x @ W[rel] + b[rel]
// One block (128 threads) per neighbor. x staged in LDS; thread t owns
// output column t (coalesced W reads across the wave). Also accumulates
// per-relation BN statistics with global f32 atomics.
// ---------------------------------------------------------------------------
__global__ void k_neighbor(const int* __restrict__ nbr, const int* __restrict__ rel,
                           const float* __restrict__ years, const float* __restrict__ months,
                           const float* __restrict__ days,
                           const float* __restrict__ ent,
                           const float* __restrict__ yf, const float* __restrict__ yp, const float* __restrict__ ya,
                           const float* __restrict__ mf, const float* __restrict__ mp, const float* __restrict__ ma,
                           const float* __restrict__ df, const float* __restrict__ dp, const float* __restrict__ da,
                           const float* __restrict__ W, const float* __restrict__ bias,
                           float* __restrict__ z, float* __restrict__ bn_sum,
                           float* __restrict__ bn_sumsq, float* __restrict__ bn_cnt)
{
    const int n = blockIdx.x;
    const int t = threadIdx.x;
    __shared__ float xs[DIM];

    const int ni = nbr[n];
    const int r  = rel[n];

    float xv;
    if (t < S_DIM) {
        xv = ent[(size_t)ni * S_DIM + t];
    } else {
        const int j = t - S_DIM;
        const size_t o = (size_t)ni * T_DIM + j;
        const float yr = years[n], mo = months[n], dy = days[n];
        xv = ya[o] * sinf(yf[o] * yr + yp[o])
           + ma[o] * sinf(mf[o] * mo + mp[o])
           + da[o] * sinf(df[o] * dy + dp[o]);
    }
    xs[t] = xv;
    __syncthreads();

    const float* __restrict__ Wr = W + (size_t)r * DIM * DIM;
    float acc = bias[r * DIM + t];
#pragma unroll 8
    for (int d = 0; d < DIM; ++d)
        acc = fmaf(xs[d], Wr[d * DIM + t], acc);

    z[(size_t)n * DIM + t] = acc;

    atomicAdd(&bn_sum[r * DIM + t], acc);
    atomicAdd(&bn_sumsq[r * DIM + t], acc * acc);
    if (t == 0) atomicAdd(&bn_cnt[r], 1.0f);
}

// ---------------------------------------------------------------------------
// K2: fold BN into per-(rel,dim) affine scale/shift. Singleton/empty buckets
// (cnt <= 1) get identity.
// ---------------------------------------------------------------------------
__global__ void k_stats(const float* __restrict__ bn_sum, const float* __restrict__ bn_sumsq,
                        const float* __restrict__ bn_cnt,
                        const float* __restrict__ gamma, const float* __restrict__ beta,
                        float* __restrict__ scale, float* __restrict__ shift)
{
    const int r = blockIdx.x;
    const int d = threadIdx.x;
    const int i = r * DIM + d;
    const float c = bn_cnt[r];
    const float denom = fmaxf(c, 1.0f);
    const float mean = bn_sum[i] / denom;
    const float var  = fmaxf(bn_sumsq[i] / denom - mean * mean, 0.0f);
    float sc, sh;
    if (c > 1.0f) {
        sc = gamma[i] / sqrtf(var + BN_EPS);
        sh = beta[i] - mean * sc;
    } else {
        sc = 1.0f;
        sh = 0.0f;
    }
    scale[i] = sc;
    shift[i] = sh;
}

// ---------------------------------------------------------------------------
// K3: edge pooling. Apply BN affine + ReLU on the fly, atomic accumulate into
// per-query sums + counts.
// ---------------------------------------------------------------------------
__global__ void k_pool(const int* __restrict__ pool_src, const int* __restrict__ pool_dst,
                       const int* __restrict__ rel,
                       const float* __restrict__ z,
                       const float* __restrict__ scale, const float* __restrict__ shift,
                       float* __restrict__ psum, float* __restrict__ pcnt)
{
    const int e = blockIdx.x;
    const int d = threadIdx.x;
    const int s = pool_src[e];
    const int q = pool_dst[e];
    const int r = rel[s];
    float v = z[(size_t)s * DIM + d] * scale[r * DIM + d] + shift[r * DIM + d];
    v = fmaxf(v, 0.0f);
    atomicAdd(&psum[(size_t)q * DIM + d], v);
    if (d == 0) atomicAdd(&pcnt[q], 1.0f);
}

// ---------------------------------------------------------------------------
// K4: TransE scoring: out[b] = -||emb[head] + rel_embs[rel] - emb[tail]||_2
// emb = psum / max(pcnt,1) computed on the fly. One block (128 thr) / triple.
// ---------------------------------------------------------------------------
__global__ void k_score(const int* __restrict__ head, const int* __restrict__ tail,
                        const int* __restrict__ rels,
                        const float* __restrict__ psum, const float* __restrict__ pcnt,
                        const float* __restrict__ rel_embs,
                        float* __restrict__ out)
{
    const int b = blockIdx.x;
    const int d = threadIdx.x;
    const int h = head[b], tq = tail[b], r = rels[b];

    const float hv = psum[(size_t)h  * DIM + d] / fmaxf(pcnt[h],  1.0f);
    const float tv = psum[(size_t)tq * DIM + d] / fmaxf(pcnt[tq], 1.0f);
    const float diff = hv + rel_embs[r * DIM + d] - tv;
    float sq = diff * diff;

    // reduce 128 threads = 2 waves of 64
    for (int off = 32; off > 0; off >>= 1) sq += __shfl_down(sq, off);
    __shared__ float partial[2];
    const int lane = threadIdx.x & 63;
    const int wv = threadIdx.x >> 6;
    if (lane == 0) partial[wv] = sq;
    __syncthreads();
    if (threadIdx.x == 0) out[b] = -sqrtf(partial[0] + partial[1]);
}

// ---------------------------------------------------------------------------
extern "C" void kernel_launch(void* const* d_in, const int* in_sizes, int n_in,
                              void* d_out, int out_size, void* d_ws, size_t ws_size,
                              hipStream_t stream) {
    // inputs in setup_inputs() order
    const int*   neighbor_idx = (const int*)  d_in[0];
    const int*   rel_id       = (const int*)  d_in[1];
    const float* years        = (const float*)d_in[2];
    const float* months       = (const float*)d_in[3];
    const float* days         = (const float*)d_in[4];
    const int*   pool_src     = (const int*)  d_in[5];
    const int*   pool_dst     = (const int*)  d_in[6];
    const int*   head_pos     = (const int*)  d_in[7];
    const int*   tail_pos     = (const int*)  d_in[8];
    const int*   rels         = (const int*)  d_in[9];
    const float* ent_embs     = (const float*)d_in[10];
    const float* y_freq       = (const float*)d_in[11];
    const float* y_phi        = (const float*)d_in[12];
    const float* y_amp        = (const float*)d_in[13];
    const float* m_freq       = (const float*)d_in[14];
    const float* m_phi        = (const float*)d_in[15];
    const float* m_amp        = (const float*)d_in[16];
    const float* d_freq       = (const float*)d_in[17];
    const float* d_phi        = (const float*)d_in[18];
    const float* d_amp        = (const float*)d_in[19];
    const float* rel_embs     = (const float*)d_in[20];
    const float* W            = (const float*)d_in[21];
    const float* bias         = (const float*)d_in[22];
    const float* gamma        = (const float*)d_in[23];
    const float* beta         = (const float*)d_in[24];

    float* out = (float*)d_out;

    // workspace layout (floats)
    float* ws = (float*)d_ws;
    size_t off = 0;
    float* z        = ws + off; off += (size_t)N_NBR * DIM;   // 16 MB
    float* bn_sum   = ws + off; off += (size_t)R2 * DIM;
    float* bn_sumsq = ws + off; off += (size_t)R2 * DIM;
    float* bn_cnt   = ws + off; off += (size_t)R2;
    float* scale    = ws + off; off += (size_t)R2 * DIM;
    float* shift    = ws + off; off += (size_t)R2 * DIM;
    float* psum     = ws + off; off += (size_t)Q_ENT * DIM;   // 2 MB
    float* pcnt     = ws + off; off += (size_t)Q_ENT;

    // zero the accumulators (bn_sum..bn_cnt contiguous, psum..pcnt contiguous)
    hipMemsetAsync(bn_sum, 0, ((size_t)R2 * DIM * 2 + R2) * sizeof(float), stream);
    hipMemsetAsync(psum,   0, ((size_t)Q_ENT * DIM + Q_ENT) * sizeof(float), stream);

    k_neighbor<<<N_NBR, DIM, 0, stream>>>(neighbor_idx, rel_id, years, months, days,
                                          ent_embs, y_freq, y_phi, y_amp,
                                          m_freq, m_phi, m_amp, d_freq, d_phi, d_amp,
                                          W, bias, z, bn_sum, bn_sumsq, bn_cnt);

    k_stats<<<R2, DIM, 0, stream>>>(bn_sum, bn_sumsq, bn_cnt, gamma, beta, scale, shift);

    k_pool<<<E_EDGE, DIM, 0, stream>>>(pool_src, pool_dst, rel_id, z, scale, shift, psum, pcnt);

    k_score<<<B_TRI, DIM, 0, stream>>>(head_pos, tail_pos, rels, psum, pcnt, rel_embs, out);
}

// Round 3
// 165.050 us; speedup vs baseline: 1.8510x; 1.8510x over previous
//
#include <hip/hip_runtime.h>
#include <math.h>

#define NUM_ENT 10000
#define NUM_REL 230
#define R2      460        // 2*NUM_REL
#define S_DIM   96
#define T_DIM   32
#define DIM     128
#define N_NBR   32768
#define Q_ENT   4096
#define E_EDGE  32768
#define B_TRI   1024
#define BN_EPS  1e-5f
#define NB      8          // neighbors in flight per wave

// ---------------------------------------------------------------------------
// K0a: histogram of rel_id into 460 bins
// ---------------------------------------------------------------------------
__global__ void k_hist(const int* __restrict__ rel, int* __restrict__ hist) {
    int i = blockIdx.x * blockDim.x + threadIdx.x;
    if (i < N_NBR) atomicAdd(&hist[rel[i]], 1);
}

// ---------------------------------------------------------------------------
// K0b: exclusive scan hist[460] -> offsets[461] (single block, Hillis-Steele)
// ---------------------------------------------------------------------------
__global__ void k_scan(const int* __restrict__ hist, int* __restrict__ offsets) {
    __shared__ int s[512];
    const int t = threadIdx.x;
    s[t] = (t < R2) ? hist[t] : 0;
    __syncthreads();
    for (int off = 1; off < 512; off <<= 1) {
        int a = (t >= off) ? s[t - off] : 0;
        __syncthreads();
        s[t] += a;
        __syncthreads();
    }
    if (t == 0) offsets[0] = 0;
    if (t < R2) offsets[t + 1] = s[t];
}

// ---------------------------------------------------------------------------
// K0c: scatter neighbor indices into relation-sorted order
// ---------------------------------------------------------------------------
__global__ void k_scatter(const int* __restrict__ rel, const int* __restrict__ offsets,
                          int* __restrict__ cursor, int* __restrict__ order) {
    int i = blockIdx.x * blockDim.x + threadIdx.x;
    if (i < N_NBR) {
        const int r = rel[i];
        const int pos = offsets[r] + atomicAdd(&cursor[r], 1);
        order[pos] = i;
    }
}

// ---------------------------------------------------------------------------
// K1: per-relation matvec. One block (256 thr = 4 waves) per relation.
// W[r] staged in LDS (64 KB). Each wave owns NB=8 neighbors per round:
// gather x -> LDS, then lane l accumulates output cols l and l+64 for all 8
// neighbors (W LDS read amortized 8x). BN sums reduced in registers,
// 8 atomics per block at the end. 80 KB LDS -> 2 blocks/CU.
// ---------------------------------------------------------------------------
__global__ __launch_bounds__(256, 2) void k_matvec(
    const int* __restrict__ order, const int* __restrict__ offsets,
    const int* __restrict__ nbr,
    const float* __restrict__ years, const float* __restrict__ months, const float* __restrict__ days,
    const float* __restrict__ ent,
    const float* __restrict__ yf, const float* __restrict__ yp, const float* __restrict__ ya,
    const float* __restrict__ mf, const float* __restrict__ mp, const float* __restrict__ ma,
    const float* __restrict__ df, const float* __restrict__ dp, const float* __restrict__ da,
    const float* __restrict__ W, const float* __restrict__ bias,
    float* __restrict__ z, float* __restrict__ bn_sum, float* __restrict__ bn_sumsq)
{
    const int r = blockIdx.x;
    const int start = offsets[r];
    const int cnt = offsets[r + 1] - start;
    if (cnt == 0) return;

    __shared__ __align__(16) float Wl[DIM * DIM];
    __shared__ __align__(16) float xsl[4][NB][DIM];

    {
        const float4* __restrict__ Wg = (const float4*)(W + (size_t)r * DIM * DIM);
        float4* Wl4 = (float4*)Wl;
        #pragma unroll
        for (int i = 0; i < 16; ++i)
            Wl4[threadIdx.x + i * 256] = Wg[threadIdx.x + i * 256];
    }

    const int wave = threadIdx.x >> 6;
    const int lane = threadIdx.x & 63;
    const float b0 = bias[r * DIM + lane];
    const float b1 = bias[r * DIM + lane + 64];

    float sum0 = 0.f, sq0 = 0.f, sum1 = 0.f, sq1 = 0.f;

    const int gmax = (cnt + 4 * NB - 1) / (4 * NB);
    __syncthreads();

    for (int g = 0; g < gmax; ++g) {
        const int base = g * 4 * NB + wave * NB;

        // ---- gather phase: x features for this wave's NB neighbors -> LDS
        #pragma unroll
        for (int nb = 0; nb < NB; ++nb) {
            const int idx = base + nb;
            float f0 = 0.f, f1 = 0.f;
            if (idx < cnt) {
                const int n  = order[start + idx];     // wave-uniform -> scalar loads
                const int ni = nbr[n];
                f0 = ent[ni * S_DIM + lane];           // cols 0..63: entity emb
                if (lane < 32) {
                    f1 = ent[ni * S_DIM + 64 + lane];  // cols 64..95: entity emb
                } else {
                    const int o = ni * T_DIM + (lane - 32);  // cols 96..127: time emb
                    const float yr = years[n], mo = months[n], dy = days[n];
                    f1 = ya[o] * sinf(yf[o] * yr + yp[o])
                       + ma[o] * sinf(mf[o] * mo + mp[o])
                       + da[o] * sinf(df[o] * dy + dp[o]);
                }
            }
            xsl[wave][nb][lane]      = f0;
            xsl[wave][nb][lane + 64] = f1;
        }
        __syncthreads();

        // ---- compute phase: 2 output cols per lane, 8 neighbors in flight
        float acc0[NB], acc1[NB];
        #pragma unroll
        for (int nb = 0; nb < NB; ++nb) { acc0[nb] = 0.f; acc1[nb] = 0.f; }

        #pragma unroll 8
        for (int d4 = 0; d4 < 32; ++d4) {
            float4 xv[NB];
            #pragma unroll
            for (int nb = 0; nb < NB; ++nb)
                xv[nb] = *(const float4*)&xsl[wave][nb][d4 * 4];
            #pragma unroll
            for (int k = 0; k < 4; ++k) {
                const float w0 = Wl[(d4 * 4 + k) * DIM + lane];
                const float w1 = Wl[(d4 * 4 + k) * DIM + lane + 64];
                #pragma unroll
                for (int nb = 0; nb < NB; ++nb) {
                    const float x = (k == 0) ? xv[nb].x : (k == 1) ? xv[nb].y
                                  : (k == 2) ? xv[nb].z : xv[nb].w;
                    acc0[nb] = fmaf(x, w0, acc0[nb]);
                    acc1[nb] = fmaf(x, w1, acc1[nb]);
                }
            }
        }

        // ---- epilogue: bias, z write, BN partial sums
        #pragma unroll
        for (int nb = 0; nb < NB; ++nb) {
            const int idx = base + nb;
            if (idx < cnt) {
                const int n = order[start + idx];
                const float v0 = acc0[nb] + b0;
                const float v1 = acc1[nb] + b1;
                z[(size_t)n * DIM + lane]      = v0;
                z[(size_t)n * DIM + lane + 64] = v1;
                sum0 += v0; sq0 += v0 * v0;
                sum1 += v1; sq1 += v1 * v1;
            }
        }
        __syncthreads();
    }

    atomicAdd(&bn_sum[r * DIM + lane],        sum0);
    atomicAdd(&bn_sum[r * DIM + lane + 64],   sum1);
    atomicAdd(&bn_sumsq[r * DIM + lane],      sq0);
    atomicAdd(&bn_sumsq[r * DIM + lane + 64], sq1);
}

// ---------------------------------------------------------------------------
// K2: fold BN into affine scale/shift per (rel,dim). cnt<=1 -> identity.
// ---------------------------------------------------------------------------
__global__ void k_stats(const float* __restrict__ bn_sum, const float* __restrict__ bn_sumsq,
                        const int* __restrict__ hist,
                        const float* __restrict__ gamma, const float* __restrict__ beta,
                        float* __restrict__ scale, float* __restrict__ shift)
{
    const int r = blockIdx.x;
    const int d = threadIdx.x;
    const int i = r * DIM + d;
    const int c = hist[r];
    const float denom = (float)max(c, 1);
    const float mean = bn_sum[i] / denom;
    const float var  = fmaxf(bn_sumsq[i] / denom - mean * mean, 0.0f);
    float sc, sh;
    if (c > 1) {
        sc = gamma[i] * rsqrtf(var + BN_EPS);
        sh = beta[i] - mean * sc;
    } else {
        sc = 1.0f;
        sh = 0.0f;
    }
    scale[i] = sc;
    shift[i] = sh;
}

// ---------------------------------------------------------------------------
// K3: edge pooling with fused BN affine + ReLU, atomics into psum/pcnt
// ---------------------------------------------------------------------------
__global__ void k_pool(const int* __restrict__ pool_src, const int* __restrict__ pool_dst,
                       const int* __restrict__ rel,
                       const float* __restrict__ z,
                       const float* __restrict__ scale, const float* __restrict__ shift,
                       float* __restrict__ psum, float* __restrict__ pcnt)
{
    const int e = blockIdx.x;
    const int d = threadIdx.x;
    const int s = pool_src[e];
    const int q = pool_dst[e];
    const int r = rel[s];
    float v = z[(size_t)s * DIM + d] * scale[r * DIM + d] + shift[r * DIM + d];
    v = fmaxf(v, 0.0f);
    atomicAdd(&psum[(size_t)q * DIM + d], v);
    if (d == 0) atomicAdd(&pcnt[q], 1.0f);
}

// ---------------------------------------------------------------------------
// K4: TransE scoring
// ---------------------------------------------------------------------------
__global__ void k_score(const int* __restrict__ head, const int* __restrict__ tail,
                        const int* __restrict__ rels,
                        const float* __restrict__ psum, const float* __restrict__ pcnt,
                        const float* __restrict__ rel_embs,
                        float* __restrict__ out)
{
    const int b = blockIdx.x;
    const int d = threadIdx.x;
    const int h = head[b], tq = tail[b], r = rels[b];

    const float hv = psum[(size_t)h  * DIM + d] / fmaxf(pcnt[h],  1.0f);
    const float tv = psum[(size_t)tq * DIM + d] / fmaxf(pcnt[tq], 1.0f);
    const float diff = hv + rel_embs[r * DIM + d] - tv;
    float sq = diff * diff;

    for (int off = 32; off > 0; off >>= 1) sq += __shfl_down(sq, off);
    __shared__ float partial[2];
    const int lane = threadIdx.x & 63;
    const int wv = threadIdx.x >> 6;
    if (lane == 0) partial[wv] = sq;
    __syncthreads();
    if (threadIdx.x == 0) out[b] = -sqrtf(partial[0] + partial[1]);
}

// ---------------------------------------------------------------------------
extern "C" void kernel_launch(void* const* d_in, const int* in_sizes, int n_in,
                              void* d_out, int out_size, void* d_ws, size_t ws_size,
                              hipStream_t stream) {
    const int*   neighbor_idx = (const int*)  d_in[0];
    const int*   rel_id       = (const int*)  d_in[1];
    const float* years        = (const float*)d_in[2];
    const float* months       = (const float*)d_in[3];
    const float* days         = (const float*)d_in[4];
    const int*   pool_src     = (const int*)  d_in[5];
    const int*   pool_dst     = (const int*)  d_in[6];
    const int*   head_pos     = (const int*)  d_in[7];
    const int*   tail_pos     = (const int*)  d_in[8];
    const int*   rels         = (const int*)  d_in[9];
    const float* ent_embs     = (const float*)d_in[10];
    const float* y_freq       = (const float*)d_in[11];
    const float* y_phi        = (const float*)d_in[12];
    const float* y_amp        = (const float*)d_in[13];
    const float* m_freq       = (const float*)d_in[14];
    const float* m_phi        = (const float*)d_in[15];
    const float* m_amp        = (const float*)d_in[16];
    const float* d_freq       = (const float*)d_in[17];
    const float* d_phi        = (const float*)d_in[18];
    const float* d_amp        = (const float*)d_in[19];
    const float* rel_embs     = (const float*)d_in[20];
    const float* W            = (const float*)d_in[21];
    const float* bias         = (const float*)d_in[22];
    const float* gamma        = (const float*)d_in[23];
    const float* beta         = (const float*)d_in[24];

    float* out = (float*)d_out;

    // workspace layout (4-byte units); bn_sum..pcnt is one contiguous
    // zeroed region, hist..cursor another.
    float* ws = (float*)d_ws;
    size_t off = 0;
    float* z        = ws + off; off += (size_t)N_NBR * DIM;    // 16 MB
    float* bn_sum   = ws + off; off += (size_t)R2 * DIM;
    float* bn_sumsq = ws + off; off += (size_t)R2 * DIM;
    float* psum     = ws + off; off += (size_t)Q_ENT * DIM;
    float* pcnt     = ws + off; off += (size_t)Q_ENT;
    float* scale    = ws + off; off += (size_t)R2 * DIM;
    float* shift    = ws + off; off += (size_t)R2 * DIM;
    int* hist    = (int*)(ws + off); off += R2;
    int* cursor  = (int*)(ws + off); off += R2;
    int* offsets = (int*)(ws + off); off += R2 + 1;
    int* order   = (int*)(ws + off); off += N_NBR;

    const size_t zero1 = ((size_t)R2 * DIM * 2 + (size_t)Q_ENT * DIM + Q_ENT) * sizeof(float);
    hipMemsetAsync(bn_sum, 0, zero1, stream);
    hipMemsetAsync(hist,   0, (size_t)2 * R2 * sizeof(int), stream);

    k_hist<<<(N_NBR + 255) / 256, 256, 0, stream>>>(rel_id, hist);
    k_scan<<<1, 512, 0, stream>>>(hist, offsets);
    k_scatter<<<(N_NBR + 255) / 256, 256, 0, stream>>>(rel_id, offsets, cursor, order);

    k_matvec<<<R2, 256, 0, stream>>>(order, offsets, neighbor_idx,
                                     years, months, days, ent_embs,
                                     y_freq, y_phi, y_amp,
                                     m_freq, m_phi, m_amp,
                                     d_freq, d_phi, d_amp,
                                     W, bias, z, bn_sum, bn_sumsq);

    k_stats<<<R2, DIM, 0, stream>>>(bn_sum, bn_sumsq, hist, gamma, beta, scale, shift);

    k_pool<<<E_EDGE, DIM, 0, stream>>>(pool_src, pool_dst, rel_id, z, scale, shift, psum, pcnt);

    k_score<<<B_TRI, DIM, 0, stream>>>(head_pos, tail_pos, rels, psum, pcnt, rel_embs, out);
}

// Round 4
// 96.391 us; speedup vs baseline: 3.1694x; 1.7123x over previous
//
#include <hip/hip_runtime.h>
#include <math.h>

#define NUM_ENT 10000
#define NUM_REL 230
#define R2      460
#define S_DIM   96
#define T_DIM   32
#define DIM     128
#define N_NBR   32768
#define Q_ENT   4096
#define E_EDGE  32768
#define B_TRI   1024
#define BN_EPS  1e-5f
#define CHUNK   32
#define MAXB    (N_NBR / CHUNK + R2)   // 1484 upper bound on matvec blocks

typedef __attribute__((ext_vector_type(8))) short bf16x8;
typedef __attribute__((ext_vector_type(4))) float f32x4;

// f32 -> bf16 round-to-nearest-even
__device__ __forceinline__ unsigned short f2bf(float f) {
    unsigned int u = __float_as_uint(f);
    u = (u + 0x7FFFu + ((u >> 16) & 1u)) >> 16;
    return (unsigned short)u;
}

// LDS index swizzles (ushort units).
// W LDS: [k][n] bf16. XOR spreads banks so B-frag u16 reads (fixed j, lanes
// vary n(16) x g(4)) land on 32 distinct banks.
__device__ __forceinline__ int WIDX(int k, int n) {
    return (k * DIM + n) ^ (((k & 7) << 3) ^ (((k >> 3) & 3) << 4));
}
// X LDS: [m][d] bf16. XOR breaks the 256B row stride for A-frag b128 reads.
__device__ __forceinline__ int XIDX(int m, int d) {
    return (m * DIM + d) ^ ((m & 7) << 3);
}

// ---------------------------------------------------------------------------
// K0a: fused histograms: rel_id -> 460 bins, pool_dst -> 4096 bins
// ---------------------------------------------------------------------------
__global__ void k_hist(const int* __restrict__ rel, const int* __restrict__ pdst,
                       int* __restrict__ hist_rel, int* __restrict__ hist_dst) {
    int i = blockIdx.x * blockDim.x + threadIdx.x;
    if (i < N_NBR) atomicAdd(&hist_rel[rel[i]], 1);
    if (i < E_EDGE) atomicAdd(&hist_dst[pdst[i]], 1);
}

// ---------------------------------------------------------------------------
// K0b: scan rel hist -> offsets[461]; also scan ceil(cnt/32) -> blk_off[461]
// ---------------------------------------------------------------------------
__global__ void k_scan_rel(const int* __restrict__ hist, int* __restrict__ offsets,
                           int* __restrict__ blk_off) {
    __shared__ int s[512];
    const int t = threadIdx.x;
    const int h = (t < R2) ? hist[t] : 0;
    s[t] = h;
    __syncthreads();
    for (int off = 1; off < 512; off <<= 1) {
        int a = (t >= off) ? s[t - off] : 0;
        __syncthreads();
        s[t] += a;
        __syncthreads();
    }
    if (t == 0) offsets[0] = 0;
    if (t < R2) offsets[t + 1] = s[t];
    __syncthreads();
    const int hb = (t < R2) ? (h + CHUNK - 1) / CHUNK : 0;
    s[t] = hb;
    __syncthreads();
    for (int off = 1; off < 512; off <<= 1) {
        int a = (t >= off) ? s[t - off] : 0;
        __syncthreads();
        s[t] += a;
        __syncthreads();
    }
    if (t == 0) blk_off[0] = 0;
    if (t < R2) blk_off[t + 1] = s[t];
}

// ---------------------------------------------------------------------------
// K0c: scan dst hist (4096 bins) -> dst_off[4097]. 1024 threads x 4 elems.
// ---------------------------------------------------------------------------
__global__ void k_scan_dst(const int* __restrict__ hist, int* __restrict__ offs) {
    __shared__ int s[1024];
    const int t = threadIdx.x;
    const int base = t * 4;
    int v0 = hist[base], v1 = hist[base + 1], v2 = hist[base + 2], v3 = hist[base + 3];
    s[t] = v0 + v1 + v2 + v3;
    __syncthreads();
    for (int off = 1; off < 1024; off <<= 1) {
        int a = (t >= off) ? s[t - off] : 0;
        __syncthreads();
        s[t] += a;
        __syncthreads();
    }
    int run = (t > 0) ? s[t - 1] : 0;
    offs[base] = run; run += v0;
    offs[base + 1] = run; run += v1;
    offs[base + 2] = run; run += v2;
    offs[base + 3] = run; run += v3;
    if (t == 1023) offs[4096] = run;
}

// ---------------------------------------------------------------------------
// K0d: scatter: rel-sorted neighbor order + dst-sorted edge order
// ---------------------------------------------------------------------------
__global__ void k_scatter(const int* __restrict__ rel, const int* __restrict__ offsets,
                          int* __restrict__ cur_rel, int* __restrict__ order,
                          const int* __restrict__ pdst, const int* __restrict__ dst_off,
                          int* __restrict__ cur_dst, int* __restrict__ eorder) {
    int i = blockIdx.x * blockDim.x + threadIdx.x;
    if (i < N_NBR) {
        const int r = rel[i];
        order[offsets[r] + atomicAdd(&cur_rel[r], 1)] = i;
    }
    if (i < E_EDGE) {
        const int q = pdst[i];
        eorder[dst_off[q] + atomicAdd(&cur_dst[q], 1)] = i;
    }
}

// ---------------------------------------------------------------------------
// K0e: block -> relation map for the matvec grid
// ---------------------------------------------------------------------------
__global__ void k_blockmap(const int* __restrict__ blk_off, int* __restrict__ map) {
    int r = blockIdx.x * blockDim.x + threadIdx.x;
    if (r < R2)
        for (int b = blk_off[r]; b < blk_off[r + 1]; ++b) map[b] = r;
}

// ---------------------------------------------------------------------------
// K1: MFMA matvec. One block = one 32-neighbor chunk of one relation.
// W[r] f32 -> bf16 into swizzled LDS [128k][128n] (32 KB); X chunk gathered
// (entity + diachronic sin features) as bf16 into swizzled LDS [32m][128d]
// (8 KB). 4 waves x (2 Mtile x 2 Ntile x 4 Kstep) mfma_f32_16x16x32_bf16.
// Epilogue: +bias, z store (valid rows), BN column sums via shfl + atomics.
// ---------------------------------------------------------------------------
__global__ __launch_bounds__(256, 3) void k_matvec(
    const int* __restrict__ map, const int* __restrict__ blk_off,
    const int* __restrict__ order, const int* __restrict__ offsets,
    const int* __restrict__ nbr,
    const float* __restrict__ years, const float* __restrict__ months, const float* __restrict__ days,
    const float* __restrict__ ent,
    const float* __restrict__ yf, const float* __restrict__ yp, const float* __restrict__ ya,
    const float* __restrict__ mf, const float* __restrict__ mp, const float* __restrict__ ma,
    const float* __restrict__ df, const float* __restrict__ dp, const float* __restrict__ da,
    const float* __restrict__ W, const float* __restrict__ bias,
    float* __restrict__ z, float* __restrict__ bn_sum, float* __restrict__ bn_sumsq)
{
    if (blockIdx.x >= blk_off[R2]) return;
    const int r     = map[blockIdx.x];
    const int chunk = blockIdx.x - blk_off[r];
    const int start = offsets[r];
    const int cnt   = offsets[r + 1] - start;
    const int cbase = chunk * CHUNK;
    const int mcnt  = min(CHUNK, cnt - cbase);   // valid rows in this chunk

    __shared__ __align__(16) unsigned short Wl[DIM * DIM];   // 32 KB
    __shared__ __align__(16) unsigned short Xl[CHUNK * DIM]; // 8 KB
    __shared__ int s_ord[CHUNK];
    __shared__ int s_ni[CHUNK];

    const int t = threadIdx.x;

    // ---- neighbor ids for this chunk
    if (t < CHUNK) {
        int o = -1, ni = 0;
        if (t < mcnt) { o = order[start + cbase + t]; ni = nbr[o]; }
        s_ord[t] = o;
        s_ni[t]  = ni;
    }

    // ---- stage W[r] f32 -> bf16 swizzled LDS (coalesced b128 reads)
    {
        const float* Wr = W + (size_t)r * DIM * DIM;
        #pragma unroll
        for (int i = 0; i < 16; ++i) {
            const int c  = t + i * 256;        // chunk of 4 floats
            const int k  = c >> 5;
            const int n4 = (c & 31) * 4;
            const float4 w = *(const float4*)(Wr + k * DIM + n4);
            ushort4 b;
            b.x = f2bf(w.x); b.y = f2bf(w.y); b.z = f2bf(w.z); b.w = f2bf(w.w);
            *(ushort4*)&Wl[WIDX(k, n4)] = b;
        }
    }
    __syncthreads();   // s_ni ready for gather

    // ---- gather X: entity part (phase 1): 32 nbr x 96 dims
    {
        const int m = t >> 3, s = t & 7;
        const int ni = s_ni[m];
        const bool vm = (m < mcnt);
        #pragma unroll
        for (int kk = 0; kk < 3; ++kk) {
            const int d = 4 * (s + 8 * kk);
            float4 e = *(const float4*)(ent + (size_t)ni * S_DIM + d);
            ushort4 b;
            b.x = vm ? f2bf(e.x) : 0; b.y = vm ? f2bf(e.y) : 0;
            b.z = vm ? f2bf(e.z) : 0; b.w = vm ? f2bf(e.w) : 0;
            *(ushort4*)&Xl[XIDX(m, d)] = b;
        }
    }
    // ---- gather X: time part (phase 2): 32 nbr x 32 dims, 4 dims/thread
    {
        const int m = t >> 3, j0 = (t & 7) * 4;
        const int o = s_ord[m] < 0 ? 0 : s_ord[m];
        const int ni = s_ni[m];
        const bool vm = (m < mcnt);
        const float yr = years[o], mo = months[o], dy = days[o];
        const size_t tb = (size_t)ni * T_DIM + j0;
        const float4 vyf = *(const float4*)(yf + tb), vyp = *(const float4*)(yp + tb), vya = *(const float4*)(ya + tb);
        const float4 vmf = *(const float4*)(mf + tb), vmp = *(const float4*)(mp + tb), vma = *(const float4*)(ma + tb);
        const float4 vdf = *(const float4*)(df + tb), vdp = *(const float4*)(dp + tb), vda = *(const float4*)(da + tb);
        ushort4 b;
        #pragma unroll
        for (int j = 0; j < 4; ++j) {
            const float fy = ((const float*)&vyf)[j] * yr + ((const float*)&vyp)[j];
            const float fm = ((const float*)&vmf)[j] * mo + ((const float*)&vmp)[j];
            const float fd = ((const float*)&vdf)[j] * dy + ((const float*)&vdp)[j];
            float v = ((const float*)&vya)[j] * sinf(fy)
                    + ((const float*)&vma)[j] * sinf(fm)
                    + ((const float*)&vda)[j] * sinf(fd);
            ((unsigned short*)&b)[j] = vm ? f2bf(v) : 0;
        }
        *(ushort4*)&Xl[XIDX(m, S_DIM + j0)] = b;
    }
    __syncthreads();

    // ---- MFMA: wave w owns output cols [32w, 32w+32)
    const int wv = t >> 6;
    const int lane = t & 63;
    const int l15 = lane & 15;
    const int g = lane >> 4;

    f32x4 acc[2][2];
    #pragma unroll
    for (int i = 0; i < 2; ++i)
        #pragma unroll
        for (int j = 0; j < 2; ++j) acc[i][j] = (f32x4)0.f;

    #pragma unroll
    for (int kk = 0; kk < 4; ++kk) {
        const int k0 = kk * 32;
        const bf16x8 a0 = *(const bf16x8*)&Xl[XIDX(l15,      k0 + 8 * g)];
        const bf16x8 a1 = *(const bf16x8*)&Xl[XIDX(16 + l15, k0 + 8 * g)];
        bf16x8 b0, b1;
        const int n0 = 32 * wv + l15;
        #pragma unroll
        for (int j = 0; j < 8; ++j) {
            b0[j] = (short)Wl[WIDX(k0 + 8 * g + j, n0)];
            b1[j] = (short)Wl[WIDX(k0 + 8 * g + j, n0 + 16)];
        }
        acc[0][0] = __builtin_amdgcn_mfma_f32_16x16x32_bf16(a0, b0, acc[0][0], 0, 0, 0);
        acc[0][1] = __builtin_amdgcn_mfma_f32_16x16x32_bf16(a0, b1, acc[0][1], 0, 0, 0);
        acc[1][0] = __builtin_amdgcn_mfma_f32_16x16x32_bf16(a1, b0, acc[1][0], 0, 0, 0);
        acc[1][1] = __builtin_amdgcn_mfma_f32_16x16x32_bf16(a1, b1, acc[1][1], 0, 0, 0);
    }

    // ---- epilogue: bias, z store, BN column sums
    #pragma unroll
    for (int nt = 0; nt < 2; ++nt) {
        const int nn = 32 * wv + 16 * nt + l15;
        const float bv = bias[r * DIM + nn];
        float lsum = 0.f, lsq = 0.f;
        #pragma unroll
        for (int mt = 0; mt < 2; ++mt) {
            #pragma unroll
            for (int reg = 0; reg < 4; ++reg) {
                const int ml = mt * 16 + 4 * g + reg;
                const float v = acc[mt][nt][reg] + bv;
                if (ml < mcnt) {
                    z[(size_t)s_ord[ml] * DIM + nn] = v;
                    lsum += v;
                    lsq  += v * v;
                }
            }
        }
        lsum += __shfl_xor(lsum, 16); lsum += __shfl_xor(lsum, 32);
        lsq  += __shfl_xor(lsq, 16);  lsq  += __shfl_xor(lsq, 32);
        if (g == 0) {
            atomicAdd(&bn_sum[r * DIM + nn],   lsum);
            atomicAdd(&bn_sumsq[r * DIM + nn], lsq);
        }
    }
}

// ---------------------------------------------------------------------------
// K2: fold BN into affine scale/shift per (rel,dim). cnt<=1 -> identity.
// ---------------------------------------------------------------------------
__global__ void k_stats(const float* __restrict__ bn_sum, const float* __restrict__ bn_sumsq,
                        const int* __restrict__ hist,
                        const float* __restrict__ gamma, const float* __restrict__ beta,
                        float* __restrict__ scale, float* __restrict__ shift)
{
    const int r = blockIdx.x;
    const int d = threadIdx.x;
    const int i = r * DIM + d;
    const int c = hist[r];
    const float denom = (float)max(c, 1);
    const float mean = bn_sum[i] / denom;
    const float var  = fmaxf(bn_sumsq[i] / denom - mean * mean, 0.0f);
    float sc, sh;
    if (c > 1) {
        sc = gamma[i] * rsqrtf(var + BN_EPS);
        sh = beta[i] - mean * sc;
    } else {
        sc = 1.0f;
        sh = 0.0f;
    }
    scale[i] = sc;
    shift[i] = sh;
}

// ---------------------------------------------------------------------------
// K3: atomic-free pooling: one block per query, edges pre-sorted by dst.
// emb[q][d] = avg over edges of relu(z*scale+shift); count fused.
// ---------------------------------------------------------------------------
__global__ void k_pool2(const int* __restrict__ eorder, const int* __restrict__ dst_off,
                        const int* __restrict__ pool_src, const int* __restrict__ rel,
                        const float* __restrict__ z,
                        const float* __restrict__ scale, const float* __restrict__ shift,
                        float* __restrict__ emb)
{
    const int q = blockIdx.x;
    const int d = threadIdx.x;
    const int e0 = dst_off[q], e1 = dst_off[q + 1];
    float acc = 0.f;
    for (int e = e0; e < e1; ++e) {
        const int s = pool_src[eorder[e]];
        const int r = rel[s];
        const float v = z[(size_t)s * DIM + d] * scale[r * DIM + d] + shift[r * DIM + d];
        acc += fmaxf(v, 0.f);
    }
    emb[(size_t)q * DIM + d] = (e1 > e0) ? acc / (float)(e1 - e0) : 0.f;
}

// ---------------------------------------------------------------------------
// K4: TransE scoring
// ---------------------------------------------------------------------------
__global__ void k_score(const int* __restrict__ head, const int* __restrict__ tail,
                        const int* __restrict__ rels,
                        const float* __restrict__ emb, const float* __restrict__ rel_embs,
                        float* __restrict__ out)
{
    const int b = blockIdx.x;
    const int d = threadIdx.x;
    const int h = head[b], tq = tail[b], r = rels[b];

    const float diff = emb[(size_t)h * DIM + d] + rel_embs[r * DIM + d]
                     - emb[(size_t)tq * DIM + d];
    float sq = diff * diff;
    for (int off = 32; off > 0; off >>= 1) sq += __shfl_down(sq, off);
    __shared__ float partial[2];
    if ((threadIdx.x & 63) == 0) partial[threadIdx.x >> 6] = sq;
    __syncthreads();
    if (threadIdx.x == 0) out[b] = -sqrtf(partial[0] + partial[1]);
}

// ---------------------------------------------------------------------------
extern "C" void kernel_launch(void* const* d_in, const int* in_sizes, int n_in,
                              void* d_out, int out_size, void* d_ws, size_t ws_size,
                              hipStream_t stream) {
    const int*   neighbor_idx = (const int*)  d_in[0];
    const int*   rel_id       = (const int*)  d_in[1];
    const float* years        = (const float*)d_in[2];
    const float* months       = (const float*)d_in[3];
    const float* days         = (const float*)d_in[4];
    const int*   pool_src     = (const int*)  d_in[5];
    const int*   pool_dst     = (const int*)  d_in[6];
    const int*   head_pos     = (const int*)  d_in[7];
    const int*   tail_pos     = (const int*)  d_in[8];
    const int*   rels         = (const int*)  d_in[9];
    const float* ent_embs     = (const float*)d_in[10];
    const float* y_freq       = (const float*)d_in[11];
    const float* y_phi        = (const float*)d_in[12];
    const float* y_amp        = (const float*)d_in[13];
    const float* m_freq       = (const float*)d_in[14];
    const float* m_phi        = (const float*)d_in[15];
    const float* m_amp        = (const float*)d_in[16];
    const float* d_freq       = (const float*)d_in[17];
    const float* d_phi        = (const float*)d_in[18];
    const float* d_amp        = (const float*)d_in[19];
    const float* rel_embs     = (const float*)d_in[20];
    const float* W            = (const float*)d_in[21];
    const float* bias         = (const float*)d_in[22];
    const float* gamma        = (const float*)d_in[23];
    const float* beta         = (const float*)d_in[24];

    float* out = (float*)d_out;

    // workspace layout (4-byte units). bn_sum..cur_dst is ONE contiguous
    // zeroed region (single memset).
    float* ws = (float*)d_ws;
    size_t off = 0;
    float* bn_sum   = ws + off; off += (size_t)R2 * DIM;
    float* bn_sumsq = ws + off; off += (size_t)R2 * DIM;
    int* hist_rel = (int*)(ws + off); off += R2;
    int* hist_dst = (int*)(ws + off); off += Q_ENT;
    int* cur_rel  = (int*)(ws + off); off += R2;
    int* cur_dst  = (int*)(ws + off); off += Q_ENT;
    const size_t zero_bytes = off * sizeof(float);
    int* offsets = (int*)(ws + off); off += R2 + 1;
    int* blk_off = (int*)(ws + off); off += R2 + 1;
    int* dst_off = (int*)(ws + off); off += Q_ENT + 1;
    int* order   = (int*)(ws + off); off += N_NBR;
    int* eorder  = (int*)(ws + off); off += E_EDGE;
    int* map     = (int*)(ws + off); off += MAXB;
    float* scale = ws + off; off += (size_t)R2 * DIM;
    float* shift = ws + off; off += (size_t)R2 * DIM;
    float* emb   = ws + off; off += (size_t)Q_ENT * DIM;
    float* z     = ws + off; off += (size_t)N_NBR * DIM;   // 16 MB

    hipMemsetAsync(bn_sum, 0, zero_bytes, stream);

    k_hist<<<(N_NBR + 255) / 256, 256, 0, stream>>>(rel_id, pool_dst, hist_rel, hist_dst);
    k_scan_rel<<<1, 512, 0, stream>>>(hist_rel, offsets, blk_off);
    k_scan_dst<<<1, 1024, 0, stream>>>(hist_dst, dst_off);
    k_scatter<<<(N_NBR + 255) / 256, 256, 0, stream>>>(rel_id, offsets, cur_rel, order,
                                                       pool_dst, dst_off, cur_dst, eorder);
    k_blockmap<<<2, 256, 0, stream>>>(blk_off, map);

    k_matvec<<<MAXB, 256, 0, stream>>>(map, blk_off, order, offsets, neighbor_idx,
                                       years, months, days, ent_embs,
                                       y_freq, y_phi, y_amp,
                                       m_freq, m_phi, m_amp,
                                       d_freq, d_phi, d_amp,
                                       W, bias, z, bn_sum, bn_sumsq);

    k_stats<<<R2, DIM, 0, stream>>>(bn_sum, bn_sumsq, hist_rel, gamma, beta, scale, shift);

    k_pool2<<<Q_ENT, DIM, 0, stream>>>(eorder, dst_off, pool_src, rel_id,
                                       z, scale, shift, emb);

    k_score<<<B_TRI, DIM, 0, stream>>>(head_pos, tail_pos, rels, emb, rel_embs, out);
}